// Round 3
// baseline (284.595 us; speedup 1.0000x reference)
//
#include <hip/hip_runtime.h>

#define B_IMG 32
#define N_PIX (512 * 512)
#define NB 256            // 16 octaves x 16 sub-bins (4 mantissa bits)
#define REP 8             // histogram replicas vs LDS atomic same-address serialization
#define SHIFT 19
#define LO_IDX 1840       // (exp_biased=115) << 4  => clamp range 2^-12 .. 2^3
#define BPI 32            // blocks per image
#define CHUNK (N_PIX / BPI)       // 8192 px per block
#define NBATCH (CHUNK / 4 / 256)  // 8 float4-batches per thread
#define FIXSCALE 1048576.0f       // 2^20 fixed point for packed bin sums
#define MASK40 ((1ull << 40) - 1)

// Workspace layout (all zeroed by one hipMemsetAsync before launch):
//   g_sum : u64[B_IMG][NB]   per-image fixed-point bin sums      (64 KB)
//   g_cnt : u32[B_IMG][NB]   per-image bin counts                (32 KB)
//   accs  : double[2]        global numerator / divisor
//   gcount: u32              image-finalize arrival counter
//   imgcnt: u32[B_IMG]       per-image block arrival counters
#define OFF_GSUM 0
#define OFF_GCNT (OFF_GSUM + (size_t)B_IMG * NB * 8)
#define OFF_ACCS (OFF_GCNT + (size_t)B_IMG * NB * 4)
#define OFF_GCOUNT (OFF_ACCS + 16)
#define OFF_IMGCNT (OFF_GCOUNT + 4)
#define CLEAR_BYTES (OFF_IMGCNT + 4 * B_IMG)

// ---------------- Fused: per-block histogram -> per-image atomic merge ----------------
// -> last block of each image finalizes that image; last image finalizes out[0].
// Packed LDS bins: [63:40]=count, [39:0]=sum in 2^-20 fixed pt.
// Per block: cnt<=8192 (24b ok), sum<=8192*16*2^20 < 2^38 (40b ok).
// Per image the 40-bit field would overflow (2^42) -> global merge uses split u32/u64.
__global__ __launch_bounds__(256, 4) void fused_kernel(
    const float4* __restrict__ pred, const float4* __restrict__ targ,
    const int4* __restrict__ mask,
    unsigned long long* __restrict__ g_sum, unsigned* __restrict__ g_cnt,
    double* __restrict__ accs, unsigned* __restrict__ gcount,
    unsigned* __restrict__ imgcnt, float* __restrict__ out) {
  __shared__ unsigned long long s_hist[NB * REP];   // 16 KB; re-aliased in finalize
  __shared__ bool s_last;
  __shared__ int s_bin;
  __shared__ unsigned s_cbelow;

  const int tid = threadIdx.x;
#pragma unroll
  for (int i = tid; i < NB * REP; i += 256) s_hist[i] = 0ull;
  __syncthreads();

  const int rep = tid & (REP - 1);
  const int b = blockIdx.x / BPI;                 // image index
  const int base4 = blockIdx.x * (CHUNK / 4);

#define BIN1(pp, tt, mm)                                                     \
  if ((mm) > 0) {                                                            \
    const float e = fabsf((pp) - (tt));                                      \
    int bb = (int)(__float_as_uint(e) >> SHIFT) - LO_IDX;                    \
    bb = bb < 0 ? 0 : (bb > NB - 1 ? NB - 1 : bb);                           \
    const unsigned long long pkt =                                           \
        (1ull << 40) | (unsigned long long)__float2uint_rn(e * FIXSCALE);    \
    atomicAdd(&s_hist[(bb << 3) | rep], pkt);                                \
  }

  // depth-2 software pipeline: batches j+1, j+2 in flight while binning batch j.
  // Full unroll (trip count 8) -> all p[j&1] indices compile-time (no scratch).
  float4 p[2], t[2];
  int4 m[2];
  p[0] = pred[base4 + tid]; t[0] = targ[base4 + tid]; m[0] = mask[base4 + tid];
  p[1] = pred[base4 + 256 + tid]; t[1] = targ[base4 + 256 + tid]; m[1] = mask[base4 + 256 + tid];
#pragma unroll
  for (int j = 0; j < NBATCH; ++j) {
    float4 pn, tn;
    int4 mn;
    if (j + 2 < NBATCH) {
      const int idx = base4 + (j + 2) * 256 + tid;
      pn = pred[idx]; tn = targ[idx]; mn = mask[idx];
    }
    BIN1(p[j & 1].x, t[j & 1].x, m[j & 1].x)
    BIN1(p[j & 1].y, t[j & 1].y, m[j & 1].y)
    BIN1(p[j & 1].z, t[j & 1].z, m[j & 1].z)
    BIN1(p[j & 1].w, t[j & 1].w, m[j & 1].w)
    if (j + 2 < NBATCH) { p[j & 1] = pn; t[j & 1] = tn; m[j & 1] = mn; }
  }
  __syncthreads();

  // merge replicas (exact integer adds), accumulate into per-image global hist.
  // Device-scope atomics -> cross-XCD coherent; integer adds commutative -> exact.
  {
    unsigned long long v = 0ull;
#pragma unroll
    for (int r = 0; r < REP; ++r) v += s_hist[(tid << 3) | r];
    const unsigned cc = (unsigned)(v >> 40);
    if (cc) {
      atomicAdd(&g_cnt[b * NB + tid], cc);
      atomicAdd(&g_sum[b * NB + tid], v & MASK40);
    }
  }
  __threadfence();        // release: hist atomics visible before arrival tick
  __syncthreads();
  if (tid == 0) s_last = (atomicAdd(&imgcnt[b], 1u) == (unsigned)(BPI - 1));
  __syncthreads();
  if (!s_last) return;
  __threadfence();        // acquire before reading peers' contributions

  // ---------------- per-image finalize (one block per image) ----------------
  const unsigned c = __hip_atomic_load(&g_cnt[b * NB + tid], __ATOMIC_RELAXED,
                                       __HIP_MEMORY_SCOPE_AGENT);
  const unsigned long long fx = __hip_atomic_load(&g_sum[b * NB + tid], __ATOMIC_RELAXED,
                                                  __HIP_MEMORY_SCOPE_AGENT);
  const double s = (double)fx * (1.0 / (double)FIXSCALE);

  // alias finalize scratch onto s_hist (disjoint lifetimes): scan 1KB, red 2KB
  unsigned* s_scan = (unsigned*)s_hist;               // bytes [0, 1024)
  double* s_red = (double*)(s_hist + 256);            // bytes [2048, 4096)

  s_scan[tid] = c;
  if (tid == 0) { s_bin = 0; s_cbelow = 0; }
  __syncthreads();
  // Hillis-Steele inclusive scan of counts
#pragma unroll
  for (int off = 1; off < NB; off <<= 1) {
    const unsigned add = (tid >= off) ? s_scan[tid - off] : 0u;
    __syncthreads();
    s_scan[tid] += add;
    __syncthreads();
  }
  const unsigned incl = s_scan[tid];
  const unsigned excl = incl - c;
  const unsigned M = s_scan[NB - 1];                      // all valid px land in a bin
  const unsigned k = (unsigned)floorf(0.8f * (float)M);   // matches ref's f32 floor

  if (k > 0 && excl < k && k <= incl) { s_bin = tid; s_cbelow = excl; }
  __syncthreads();

  const int bstar = s_bin;
  double acc = (tid < bstar) ? s : 0.0;   // full bins below boundary: exact sums
  if (tid == bstar && k > 0) {
    const unsigned r = k - s_cbelow;      // 1 <= r <= c
    double part;
    if (r >= c) {
      part = s;                           // exact: whole bin kept
    } else {
      const float lo = __uint_as_float((unsigned)(bstar + LO_IDX) << SHIFT);
      const double mean = s / (double)c;
      double h = mean - (double)lo;
      if (h < 0.0) h = 0.0;
      part = (double)r * (double)lo + ((double)r * (double)r / (double)c) * h;
      if (part > s) part = s;
    }
    acc += part;
  }

  // block reduce doubles
  s_red[tid] = acc;
  __syncthreads();
  for (int st = 128; st > 0; st >>= 1) {
    if (tid < st) s_red[tid] += s_red[tid + st];
    __syncthreads();
  }
  if (tid == 0) {
    atomicAdd(&accs[0], s_red[0]);                     // numerator
    atomicAdd(&accs[1], (double)(0.8f * (float)M));    // divisor term
    __threadfence();
    const unsigned old = atomicAdd(gcount, 1u);
    if (old == (unsigned)(B_IMG - 1)) {                // last image finalizes
      __threadfence();
      const double num = atomicAdd(&accs[0], 0.0);
      const double den = atomicAdd(&accs[1], 0.0);
      const double r = (den == 0.0) ? 0.0 : num / fmax(den, 1e-30);
      out[0] = (float)r;
    }
  }
}

extern "C" void kernel_launch(void* const* d_in, const int* in_sizes, int n_in,
                              void* d_out, int out_size, void* d_ws, size_t ws_size,
                              hipStream_t stream) {
  const float4* pred = (const float4*)d_in[0];
  const float4* targ = (const float4*)d_in[1];
  const int4* mask = (const int4*)d_in[2];
  float* out = (float*)d_out;

  char* ws = (char*)d_ws;
  unsigned long long* g_sum = (unsigned long long*)(ws + OFF_GSUM);
  unsigned* g_cnt = (unsigned*)(ws + OFF_GCNT);
  double* accs = (double*)(ws + OFF_ACCS);
  unsigned* gcount = (unsigned*)(ws + OFF_GCOUNT);
  unsigned* imgcnt = (unsigned*)(ws + OFF_IMGCNT);

  hipMemsetAsync(ws, 0, CLEAR_BYTES, stream);   // zero hist + counters (stream-ordered)
  fused_kernel<<<B_IMG * BPI, 256, 0, stream>>>(pred, targ, mask, g_sum, g_cnt,
                                                accs, gcount, imgcnt, out);
}

// Round 4
// 119.297 us; speedup vs baseline: 2.3856x; 2.3856x over previous
//
#include <hip/hip_runtime.h>

#define B_IMG 32
#define N_PIX (512 * 512)
#define NB 256            // 16 octaves x 16 sub-bins (4 mantissa bits)
#define REP 8             // histogram replicas vs LDS atomic same-address serialization
#define SHIFT 19
#define LO_IDX 1840       // (exp_biased=115) << 4  => clamp range 2^-12 .. 2^3
#define BPI 32            // blocks per image
#define CHUNK (N_PIX / BPI)       // 8192 px per block
#define NBATCH (CHUNK / 4 / 256)  // 8 float4-batches per thread
#define FIXSCALE 1048576.0f       // 2^20 fixed point for packed bin sums
#define MASK40 ((1ull << 40) - 1)

// ---------------- Pass 1: per-block partial histogram (packed u64, 8-way replicated) ----
// Packs per-bin {count, sum} into one u64: [63:40]=count, [39:0]=sum in 2^-20 fixed pt.
// Max per block: cnt<=8192 (24 bits ok), sum<=8192*16*2^20 < 2^38 (40 bits ok).
// Depth-3 software pipeline with NAMED registers (A/B/C rotation): ~3 batches of
// global loads in flight per wave -> 4 waves/SIMD x 3 x ~90cy > 900cy HBM latency.
__global__ __launch_bounds__(256, 4) void hist_kernel(
    const float4* __restrict__ pred, const float4* __restrict__ targ,
    const int4* __restrict__ mask, unsigned long long* __restrict__ g_part,
    double* __restrict__ accs, unsigned* __restrict__ counter) {
  __shared__ unsigned long long s_hist[NB * REP];   // 16 KB
  const int tid = threadIdx.x;
#pragma unroll
  for (int i = tid; i < NB * REP; i += 256) s_hist[i] = 0ull;
  if (blockIdx.x == 0 && tid == 0) {  // zero K2 accumulators; stream-ordered before K2
    accs[0] = 0.0; accs[1] = 0.0; *counter = 0u;
  }
  __syncthreads();

  const int rep = tid & (REP - 1);
  const int base4 = blockIdx.x * (CHUNK / 4);

#define BIN1(pp, tt, mm)                                                     \
  if ((mm) > 0) {                                                            \
    const float e = fabsf((pp) - (tt));                                      \
    int bb = (int)(__float_as_uint(e) >> SHIFT) - LO_IDX;                    \
    bb = bb < 0 ? 0 : (bb > NB - 1 ? NB - 1 : bb);                           \
    const unsigned long long pkt =                                           \
        (1ull << 40) | (unsigned long long)__float2uint_rn(e * FIXSCALE);    \
    atomicAdd(&s_hist[(bb << 3) | rep], pkt);                                \
  }

#define LOADB(vp, vt, vm, J)                              \
  {                                                       \
    const int idx_ = base4 + (J) * 256 + tid;             \
    vp = pred[idx_]; vt = targ[idx_]; vm = mask[idx_];    \
  }
#define BIN4(vp, vt, vm) \
  BIN1(vp.x, vt.x, vm.x) BIN1(vp.y, vt.y, vm.y) BIN1(vp.z, vt.z, vm.z) BIN1(vp.w, vt.w, vm.w)

  float4 pA, tA, pB, tB, pC, tC;
  int4 mA, mB, mC;
  LOADB(pA, tA, mA, 0)
  LOADB(pB, tB, mB, 1)
  LOADB(pC, tC, mC, 2)
  BIN4(pA, tA, mA) LOADB(pA, tA, mA, 3)   // j=0, prefetch j=3
  BIN4(pB, tB, mB) LOADB(pB, tB, mB, 4)   // j=1, prefetch j=4
  BIN4(pC, tC, mC) LOADB(pC, tC, mC, 5)   // j=2, prefetch j=5
  BIN4(pA, tA, mA) LOADB(pA, tA, mA, 6)   // j=3, prefetch j=6
  BIN4(pB, tB, mB) LOADB(pB, tB, mB, 7)   // j=4, prefetch j=7
  BIN4(pC, tC, mC)                        // j=5
  BIN4(pA, tA, mA)                        // j=6
  BIN4(pB, tB, mB)                        // j=7
  __syncthreads();

  // merge replicas (exact integer adds; no carry into count field since sum < 2^38)
  // then flush: plain coalesced store, no atomics, no pre-zero needed
  if (tid < NB) {
    unsigned long long v = 0ull;
#pragma unroll
    for (int r = 0; r < REP; ++r) v += s_hist[(tid << 3) | r];
    g_part[(size_t)blockIdx.x * NB + tid] = v;
  }
}

// ---------------- Pass 2: per-image selection + trimmed sum + final divide ----------------
// Wave-level shfl scan/reduce: ~4 __syncthreads total (was ~40).
__global__ __launch_bounds__(256) void finalize_kernel(
    const unsigned long long* __restrict__ g_part, double* __restrict__ accs,
    unsigned* __restrict__ counter, float* __restrict__ out) {
  const int b = blockIdx.x;
  const int tid = threadIdx.x;   // 256 threads, one bin each
  const int lane = tid & 63;
  const int w = tid >> 6;        // wave id 0..3
  const unsigned long long* base = g_part + (size_t)b * BPI * NB;

  // reduce 32 partials for this image's bin `tid` (coalesced, independent loads)
  unsigned long long fix = 0ull;
  unsigned c = 0u;
#pragma unroll 8
  for (int p = 0; p < BPI; ++p) {
    const unsigned long long v = base[(size_t)p * NB + tid];
    c += (unsigned)(v >> 40);
    fix += (v & MASK40);
  }
  const double s = (double)fix * (1.0 / (double)FIXSCALE);

  __shared__ unsigned s_wtot[4];
  __shared__ double s_dred[4];
  __shared__ int s_bin;
  __shared__ unsigned s_cbelow;

  // inclusive scan of counts: shfl within wave, then wave offsets
  unsigned v = c;
#pragma unroll
  for (int off = 1; off < 64; off <<= 1) {
    const unsigned up = __shfl_up(v, off, 64);
    if (lane >= off) v += up;
  }
  if (lane == 63) s_wtot[w] = v;
  if (tid == 0) { s_bin = 0; s_cbelow = 0; }
  __syncthreads();
  unsigned woff = 0;
#pragma unroll
  for (int i = 0; i < 3; ++i) woff += (i < w) ? s_wtot[i] : 0u;
  const unsigned incl = v + woff;
  const unsigned excl = incl - c;
  const unsigned M = s_wtot[0] + s_wtot[1] + s_wtot[2] + s_wtot[3];  // all valid px
  const unsigned k = (unsigned)floorf(0.8f * (float)M);   // matches ref's f32 floor

  if (k > 0 && excl < k && k <= incl) { s_bin = tid; s_cbelow = excl; }
  __syncthreads();

  const int bstar = s_bin;
  double acc = (tid < bstar) ? s : 0.0;   // full bins below boundary: exact sums
  if (tid == bstar && k > 0) {
    const unsigned r = k - s_cbelow;      // 1 <= r <= c
    double part;
    if (r >= c) {
      part = s;                           // exact: whole bin kept
    } else {
      const float lo = __uint_as_float((unsigned)(bstar + LO_IDX) << SHIFT);
      const double mean = s / (double)c;
      double h = mean - (double)lo;
      if (h < 0.0) h = 0.0;
      part = (double)r * (double)lo + ((double)r * (double)r / (double)c) * h;
      if (part > s) part = s;
    }
    acc += part;
  }

  // double reduce: shfl within wave, then 4 wave partials
  double x = acc;
#pragma unroll
  for (int off = 32; off > 0; off >>= 1) x += __shfl_down(x, off, 64);
  if (lane == 0) s_dred[w] = x;
  __syncthreads();
  if (tid == 0) {
    const double tot = s_dred[0] + s_dred[1] + s_dred[2] + s_dred[3];
    atomicAdd(&accs[0], tot);                          // numerator
    atomicAdd(&accs[1], (double)(0.8f * (float)M));    // divisor term
    __threadfence();
    const unsigned old = atomicAdd(counter, 1u);
    if (old == (unsigned)(B_IMG - 1)) {                // last block finalizes
      __threadfence();
      const double num = atomicAdd(&accs[0], 0.0);
      const double den = atomicAdd(&accs[1], 0.0);
      const double r = (den == 0.0) ? 0.0 : num / fmax(den, 1e-30);
      out[0] = (float)r;
    }
  }
}

extern "C" void kernel_launch(void* const* d_in, const int* in_sizes, int n_in,
                              void* d_out, int out_size, void* d_ws, size_t ws_size,
                              hipStream_t stream) {
  const float4* pred = (const float4*)d_in[0];
  const float4* targ = (const float4*)d_in[1];
  const int4* mask = (const int4*)d_in[2];
  float* out = (float*)d_out;

  char* ws = (char*)d_ws;
  unsigned long long* g_part = (unsigned long long*)ws;            // 1024*256*8 = 2 MB
  double* accs = (double*)(ws + (size_t)B_IMG * BPI * NB * 8);     // 16 B
  unsigned* counter = (unsigned*)(ws + (size_t)B_IMG * BPI * NB * 8 + 16);

  hist_kernel<<<B_IMG * BPI, 256, 0, stream>>>(pred, targ, mask, g_part, accs, counter);
  finalize_kernel<<<B_IMG, 256, 0, stream>>>(g_part, accs, counter, out);
}